// Round 1
// baseline (5598.411 us; speedup 1.0000x reference)
//
#include <hip/hip_runtime.h>

#define PLANE (1 << 20)   // 1024*1024
#define BK 16

// ---------------------------------------------------------------------------
// B = (A - A^H) * scale     (per control block k, planes are [2][1024][1024])
// ---------------------------------------------------------------------------
__global__ __launch_bounds__(256) void build_skew_k(
    const float* __restrict__ Ure, const float* __restrict__ Uim,
    float* __restrict__ Bre, float* __restrict__ Bim, float scale)
{
    int idx = blockIdx.x * 256 + threadIdx.x;        // over 2*1024*1024
    int ij  = idx & (PLANE - 1);
    int i   = ij >> 10, j = ij & 1023;
    int t   = (idx & ~(PLANE - 1)) | (j << 10) | i;  // transposed element
    Bre[idx] = (Ure[idx] - Ure[t]) * scale;
    Bim[idx] = (Uim[idx] + Uim[t]) * scale;
}

// T = I + B * inv
__global__ __launch_bounds__(256) void init_T_k(
    const float* __restrict__ Bre, const float* __restrict__ Bim,
    float* __restrict__ Tre, float* __restrict__ Tim, float inv)
{
    int idx = blockIdx.x * 256 + threadIdx.x;
    int ij  = idx & (PLANE - 1);
    int i   = ij >> 10, j = ij & 1023;
    Tre[idx] = Bre[idx] * inv + ((i == j) ? 1.0f : 0.0f);
    Tim[idx] = Bim[idx] * inv;
}

// ---------------------------------------------------------------------------
// Complex GEMM:  C = scale * (A @ B) [+ I]
// A: [1024 x 1024] row-major (lda=1024), batched via aStride (k = bz/aDiv)
// B: [1024 x N]    row-major (ldb=N),    batched via bStride
// C: [1024 x N]    row-major (ldc=N),    batched via cStride
// 64x64 block tile, 256 threads, 4x4 complex micro-tile, BK=16.
// ---------------------------------------------------------------------------
__global__ __launch_bounds__(256) void zgemm_k(
    const float* __restrict__ Are, const float* __restrict__ Aim,
    const float* __restrict__ Bre, const float* __restrict__ Bim,
    float* __restrict__ Cre, float* __restrict__ Cim,
    int N, long aStride, long bStride, long cStride, int aDiv,
    float scale, int addIdent)
{
    // A tile stored transposed [kk][m] with pad 68 (row = 272B, 16B aligned)
    __shared__ float As_re[BK][68];
    __shared__ float As_im[BK][68];
    __shared__ float Bs_re[BK][64];
    __shared__ float Bs_im[BK][64];

    const int bz = blockIdx.z;
    const float* are = Are + (size_t)(bz / aDiv) * aStride;
    const float* aim = Aim + (size_t)(bz / aDiv) * aStride;
    const float* bre = Bre + (size_t)bz * bStride;
    const float* bim = Bim + (size_t)bz * bStride;
    float* cre = Cre + (size_t)bz * cStride;
    float* cim = Cim + (size_t)bz * cStride;

    const int tid = threadIdx.x;
    const int tx = tid & 15;        // 0..15 -> 4 cols each
    const int ty = tid >> 4;        // 0..15 -> 4 rows each
    const int m0 = blockIdx.y * 64;
    const int n0 = blockIdx.x * 64;

    const int arow = tid >> 2;      // 0..63
    const int akg  = (tid & 3) * 4; // 0,4,8,12
    const int brow = tid >> 4;      // 0..15
    const int bcol = (tid & 15) * 4;

    float acc_re[4][4] = {{0.f}};
    float acc_im[4][4] = {{0.f}};

    for (int kb = 0; kb < 1024; kb += BK) {
        float4 a_r = *(const float4*)(are + (size_t)(m0 + arow) * 1024 + kb + akg);
        float4 a_i = *(const float4*)(aim + (size_t)(m0 + arow) * 1024 + kb + akg);
        float4 b_r = *(const float4*)(bre + (size_t)(kb + brow) * N + n0 + bcol);
        float4 b_i = *(const float4*)(bim + (size_t)(kb + brow) * N + n0 + bcol);

        __syncthreads();
        As_re[akg + 0][arow] = a_r.x; As_re[akg + 1][arow] = a_r.y;
        As_re[akg + 2][arow] = a_r.z; As_re[akg + 3][arow] = a_r.w;
        As_im[akg + 0][arow] = a_i.x; As_im[akg + 1][arow] = a_i.y;
        As_im[akg + 2][arow] = a_i.z; As_im[akg + 3][arow] = a_i.w;
        *(float4*)&Bs_re[brow][bcol] = b_r;
        *(float4*)&Bs_im[brow][bcol] = b_i;
        __syncthreads();

        #pragma unroll
        for (int kk = 0; kk < BK; ++kk) {
            float4 arv = *(const float4*)&As_re[kk][ty * 4];
            float4 aiv = *(const float4*)&As_im[kk][ty * 4];
            float4 brv = *(const float4*)&Bs_re[kk][tx * 4];
            float4 biv = *(const float4*)&Bs_im[kk][tx * 4];
            float ar[4] = {arv.x, arv.y, arv.z, arv.w};
            float ai[4] = {aiv.x, aiv.y, aiv.z, aiv.w};
            float br[4] = {brv.x, brv.y, brv.z, brv.w};
            float bi[4] = {biv.x, biv.y, biv.z, biv.w};
            #pragma unroll
            for (int i = 0; i < 4; ++i) {
                #pragma unroll
                for (int j = 0; j < 4; ++j) {
                    acc_re[i][j] = fmaf(ar[i], br[j], acc_re[i][j]);
                    acc_re[i][j] = fmaf(-ai[i], bi[j], acc_re[i][j]);
                    acc_im[i][j] = fmaf(ar[i], bi[j], acc_im[i][j]);
                    acc_im[i][j] = fmaf(ai[i], br[j], acc_im[i][j]);
                }
            }
        }
    }

    const int crow0 = m0 + ty * 4;
    const int ccol0 = n0 + tx * 4;
    #pragma unroll
    for (int i = 0; i < 4; ++i) {
        float4 vr, vi;
        vr.x = acc_re[i][0] * scale; vr.y = acc_re[i][1] * scale;
        vr.z = acc_re[i][2] * scale; vr.w = acc_re[i][3] * scale;
        vi.x = acc_im[i][0] * scale; vi.y = acc_im[i][1] * scale;
        vi.z = acc_im[i][2] * scale; vi.w = acc_im[i][3] * scale;
        if (addIdent) {
            int row = crow0 + i;
            int d = row - ccol0;
            if (d >= 0 && d < 4) {
                if (d == 0) vr.x += 1.f;
                else if (d == 1) vr.y += 1.f;
                else if (d == 2) vr.z += 1.f;
                else vr.w += 1.f;
            }
        }
        *(float4*)(cre + (size_t)(crow0 + i) * N + ccol0) = vr;
        *(float4*)(cim + (size_t)(crow0 + i) * N + ccol0) = vi;
    }
}

// ---------------------------------------------------------------------------
extern "C" void kernel_launch(void* const* d_in, const int* in_sizes, int n_in,
                              void* d_out, int out_size, void* d_ws, size_t ws_size,
                              hipStream_t stream)
{
    const float* x_re = (const float*)d_in[0];
    const float* x_im = (const float*)d_in[1];
    const float* U_re = (const float*)d_in[2];
    const float* U_im = (const float*)d_in[3];
    float* out = (float*)d_out;

    // Workspace: 6 planes of [2][1024][1024] fp32 = 48 MB
    float* ws  = (float*)d_ws;
    float* Bre = ws + 0L * 2 * PLANE;
    float* Bim = ws + 1L * 2 * PLANE;
    float* Tre = ws + 2L * 2 * PLANE;
    float* Tim = ws + 3L * 2 * PLANE;
    float* Rre = ws + 4L * 2 * PLANE;
    float* Rim = ws + 5L * 2 * PLANE;

    dim3 blk(256);

    // --- expm via scaling (2^-9) + degree-8 Taylor (Horner) + 9 squarings ---
    const float scaleB = 1.0f / 512.0f;   // ||skew||_2 ~ 128 -> ||B|| ~ 0.25
    build_skew_k<<<dim3(2 * PLANE / 256), blk, 0, stream>>>(U_re, U_im, Bre, Bim, scaleB);
    init_T_k<<<dim3(2 * PLANE / 256), blk, 0, stream>>>(Bre, Bim, Tre, Tim, 1.0f / 8.0f);

    dim3 g1(16, 16, 2);   // N/64, M/64, batch k
    for (int j = 7; j >= 1; --j) {
        // T <- I + (B @ T) / j
        zgemm_k<<<g1, blk, 0, stream>>>(Bre, Bim, Tre, Tim, Rre, Rim,
                                        1024, PLANE, PLANE, PLANE, 1,
                                        1.0f / (float)j, 1);
        float* t;
        t = Tre; Tre = Rre; Rre = t;
        t = Tim; Tim = Rim; Rim = t;
    }
    for (int s = 0; s < 9; ++s) {
        // T <- T @ T
        zgemm_k<<<g1, blk, 0, stream>>>(Tre, Tim, Tre, Tim, Rre, Rim,
                                        1024, PLANE, PLANE, PLANE, 1,
                                        1.0f, 0);
        float* t;
        t = Tre; Tre = Rre; Rre = t;
        t = Tim; Tim = Rim; Rim = t;
    }

    // --- apply: out[k,b1] = U[k] @ X[k,b1], X contiguous [1024 x 4096] ------
    // flat n = [k | b1 | t(10) | low12]; plane base = bz * 2^22
    dim3 g2(64, 16, 4);   // N=4096 cols, M=1024 rows, batch (k,b1)
    zgemm_k<<<g2, blk, 0, stream>>>(Tre, Tim, x_re, x_im,
                                    out, out + (1L << 24),
                                    4096, PLANE, 1L << 22, 1L << 22, 2,
                                    1.0f, 0);
}

// Round 2
// 2805.941 us; speedup vs baseline: 1.9952x; 1.9952x over previous
//
#include <hip/hip_runtime.h>
#include <hip/hip_bf16.h>

#define PLANE (1 << 20)   // 1024*1024

typedef __attribute__((ext_vector_type(8))) short bf16x8;
typedef __attribute__((ext_vector_type(4))) float f32x4;

struct SegOff { long o[6]; };

union U4 { ushort u[4]; unsigned long long v; };

__device__ __forceinline__ ushort bf16bits(float v) {
    union { __hip_bfloat16 b; ushort u; } c;
    c.b = __float2bfloat16(v);
    return c.u;
}

__device__ __forceinline__ void split2(float v, ushort& hi, ushort& lo) {
    union { __hip_bfloat16 b; ushort u; } c;
    __hip_bfloat16 h = __float2bfloat16(v);
    c.b = h; hi = c.u;
    c.b = __float2bfloat16(v - __bfloat162float(h));
    lo = c.u;
}

__device__ __forceinline__ void gload16(const ushort* g, ushort* l) {
    __builtin_amdgcn_global_load_lds(
        (const __attribute__((address_space(1))) unsigned int*)g,
        (__attribute__((address_space(3))) unsigned int*)l, 16, 0, 0);
}

// ---------------------------------------------------------------------------
// B = (A - A^H) * scale
// ---------------------------------------------------------------------------
__global__ __launch_bounds__(256) void build_skew_k(
    const float* __restrict__ Ure, const float* __restrict__ Uim,
    float* __restrict__ Bre, float* __restrict__ Bim, float scale)
{
    int idx = blockIdx.x * 256 + threadIdx.x;
    int ij  = idx & (PLANE - 1);
    int i   = ij >> 10, j = ij & 1023;
    int t   = (idx & ~(PLANE - 1)) | (j << 10) | i;
    Bre[idx] = (Ure[idx] - Ure[t]) * scale;
    Bim[idx] = (Uim[idx] + Uim[t]) * scale;
}

// T = I + B * inv
__global__ __launch_bounds__(256) void init_T_k(
    const float* __restrict__ Bre, const float* __restrict__ Bim,
    float* __restrict__ Tre, float* __restrict__ Tim, float inv)
{
    int idx = blockIdx.x * 256 + threadIdx.x;
    int ij  = idx & (PLANE - 1);
    int i   = ij >> 10, j = ij & 1023;
    Tre[idx] = Bre[idx] * inv + ((i == j) ? 1.0f : 0.0f);
    Tim[idx] = Bim[idx] * inv;
}

// ---------------------------------------------------------------------------
// Pack A (expm, 6 segments): Ab[4 z][1024][6144]
//   z = pack*2 + k
//   pack0: [Arh, Arh, Arl, -Aih, -Aih, -Ail]
//   pack1: [Aih, Aih, Ail,  Arh,  Arh,  Arl]
// ---------------------------------------------------------------------------
__global__ __launch_bounds__(256) void pack_A6_k(
    const float* __restrict__ Sre, const float* __restrict__ Sim,
    ushort* __restrict__ Ab)
{
    int idx = blockIdx.x * 256 + threadIdx.x;     // 524288 threads
    int k   = idx >> 18;
    int m   = (idx >> 8) & 1023;
    int c4  = (idx & 255) * 4;
    const float4 vr = *(const float4*)(Sre + (size_t)k * PLANE + (size_t)m * 1024 + c4);
    const float4 vi = *(const float4*)(Sim + (size_t)k * PLANE + (size_t)m * 1024 + c4);
    U4 rh, rl, ih, il, nih, nil;
    split2(vr.x, rh.u[0], rl.u[0]); split2(vr.y, rh.u[1], rl.u[1]);
    split2(vr.z, rh.u[2], rl.u[2]); split2(vr.w, rh.u[3], rl.u[3]);
    split2(vi.x, ih.u[0], il.u[0]); split2(vi.y, ih.u[1], il.u[1]);
    split2(vi.z, ih.u[2], il.u[2]); split2(vi.w, ih.u[3], il.u[3]);
    #pragma unroll
    for (int i = 0; i < 4; ++i) { nih.u[i] = ih.u[i] ^ 0x8000; nil.u[i] = il.u[i] ^ 0x8000; }

    long b0 = (long)k * 1024 * 6144 + (long)m * 6144;
    long b1 = (long)(2 + k) * 1024 * 6144 + (long)m * 6144;
    *(unsigned long long*)&Ab[b0 + 0*1024 + c4] = rh.v;
    *(unsigned long long*)&Ab[b0 + 1*1024 + c4] = rh.v;
    *(unsigned long long*)&Ab[b0 + 2*1024 + c4] = rl.v;
    *(unsigned long long*)&Ab[b0 + 3*1024 + c4] = nih.v;
    *(unsigned long long*)&Ab[b0 + 4*1024 + c4] = nih.v;
    *(unsigned long long*)&Ab[b0 + 5*1024 + c4] = nil.v;
    *(unsigned long long*)&Ab[b1 + 0*1024 + c4] = ih.v;
    *(unsigned long long*)&Ab[b1 + 1*1024 + c4] = ih.v;
    *(unsigned long long*)&Ab[b1 + 2*1024 + c4] = il.v;
    *(unsigned long long*)&Ab[b1 + 3*1024 + c4] = rh.v;
    *(unsigned long long*)&Ab[b1 + 4*1024 + c4] = rh.v;
    *(unsigned long long*)&Ab[b1 + 5*1024 + c4] = rl.v;
}

// ---------------------------------------------------------------------------
// Pack A (apply, 4 segments): Ab[4 z][1024][4096]
//   pack0: [Urh, Url, -Uih, -Uil]    pack1: [Uih, Uil, Urh, Url]
// ---------------------------------------------------------------------------
__global__ __launch_bounds__(256) void pack_A4_k(
    const float* __restrict__ Sre, const float* __restrict__ Sim,
    ushort* __restrict__ Ab)
{
    int idx = blockIdx.x * 256 + threadIdx.x;
    int k   = idx >> 18;
    int m   = (idx >> 8) & 1023;
    int c4  = (idx & 255) * 4;
    const float4 vr = *(const float4*)(Sre + (size_t)k * PLANE + (size_t)m * 1024 + c4);
    const float4 vi = *(const float4*)(Sim + (size_t)k * PLANE + (size_t)m * 1024 + c4);
    U4 rh, rl, ih, il, nih, nil;
    split2(vr.x, rh.u[0], rl.u[0]); split2(vr.y, rh.u[1], rl.u[1]);
    split2(vr.z, rh.u[2], rl.u[2]); split2(vr.w, rh.u[3], rl.u[3]);
    split2(vi.x, ih.u[0], il.u[0]); split2(vi.y, ih.u[1], il.u[1]);
    split2(vi.z, ih.u[2], il.u[2]); split2(vi.w, ih.u[3], il.u[3]);
    #pragma unroll
    for (int i = 0; i < 4; ++i) { nih.u[i] = ih.u[i] ^ 0x8000; nil.u[i] = il.u[i] ^ 0x8000; }

    long b0 = (long)k * 1024 * 4096 + (long)m * 4096;
    long b1 = (long)(2 + k) * 1024 * 4096 + (long)m * 4096;
    *(unsigned long long*)&Ab[b0 + 0*1024 + c4] = rh.v;
    *(unsigned long long*)&Ab[b0 + 1*1024 + c4] = rl.v;
    *(unsigned long long*)&Ab[b0 + 2*1024 + c4] = nih.v;
    *(unsigned long long*)&Ab[b0 + 3*1024 + c4] = nil.v;
    *(unsigned long long*)&Ab[b1 + 0*1024 + c4] = ih.v;
    *(unsigned long long*)&Ab[b1 + 1*1024 + c4] = il.v;
    *(unsigned long long*)&Ab[b1 + 2*1024 + c4] = rh.v;
    *(unsigned long long*)&Ab[b1 + 3*1024 + c4] = rl.v;
}

// ---------------------------------------------------------------------------
// Transpose + split T -> Tt[4 kind][2 k][1024][1024]  (kind: rh, rl, ih, il)
// ---------------------------------------------------------------------------
__global__ __launch_bounds__(256) void pack_BT6_k(
    const float* __restrict__ Sre, const float* __restrict__ Sim,
    ushort* __restrict__ Tt)
{
    __shared__ float Lre[64][65];
    __shared__ float Lim[64][65];
    int k = blockIdx.z, r0 = blockIdx.y * 64, c0 = blockIdx.x * 64;
    int tid = threadIdx.x;
    const float* br = Sre + (size_t)k * PLANE;
    const float* bi = Sim + (size_t)k * PLANE;
    #pragma unroll
    for (int p = 0; p < 16; ++p) {
        int idx = p * 256 + tid, r = idx >> 6, c = idx & 63;
        Lre[r][c] = br[(size_t)(r0 + r) * 1024 + c0 + c];
        Lim[r][c] = bi[(size_t)(r0 + r) * 1024 + c0 + c];
    }
    __syncthreads();
    #pragma unroll
    for (int p = 0; p < 4; ++p) {
        int s = p * 256 + tid, oc = s >> 4, r4 = (s & 15) * 4;
        U4 rh, rl, ih, il;
        #pragma unroll
        for (int i = 0; i < 4; ++i) {
            split2(Lre[r4 + i][oc], rh.u[i], rl.u[i]);
            split2(Lim[r4 + i][oc], ih.u[i], il.u[i]);
        }
        size_t dst = (size_t)k * PLANE + (size_t)(c0 + oc) * 1024 + r0 + r4;
        *(unsigned long long*)&Tt[0L * 2 * PLANE + dst] = rh.v;
        *(unsigned long long*)&Tt[1L * 2 * PLANE + dst] = rl.v;
        *(unsigned long long*)&Tt[2L * 2 * PLANE + dst] = ih.v;
        *(unsigned long long*)&Tt[3L * 2 * PLANE + dst] = il.v;
    }
}

// ---------------------------------------------------------------------------
// Transpose + convert x -> xT[2 kind][4 plane][4096][1024] (plain bf16)
// ---------------------------------------------------------------------------
__global__ __launch_bounds__(256) void pack_xT_k(
    const float* __restrict__ xre, const float* __restrict__ xim,
    ushort* __restrict__ xT)
{
    __shared__ float Lre[64][65];
    __shared__ float Lim[64][65];
    int pl = blockIdx.z, t0 = blockIdx.y * 64, c0 = blockIdx.x * 64;
    int tid = threadIdx.x;
    const float* br = xre + ((size_t)pl << 22);
    const float* bi = xim + ((size_t)pl << 22);
    #pragma unroll
    for (int p = 0; p < 16; ++p) {
        int idx = p * 256 + tid, r = idx >> 6, c = idx & 63;
        Lre[r][c] = br[(size_t)(t0 + r) * 4096 + c0 + c];
        Lim[r][c] = bi[(size_t)(t0 + r) * 4096 + c0 + c];
    }
    __syncthreads();
    #pragma unroll
    for (int p = 0; p < 4; ++p) {
        int s = p * 256 + tid, oc = s >> 4, r4 = (s & 15) * 4;
        U4 re4, im4;
        #pragma unroll
        for (int i = 0; i < 4; ++i) {
            re4.u[i] = bf16bits(Lre[r4 + i][oc]);
            im4.u[i] = bf16bits(Lim[r4 + i][oc]);
        }
        size_t dst = ((size_t)pl << 22) + (size_t)(c0 + oc) * 1024 + t0 + r4;
        *(unsigned long long*)&xT[dst] = re4.v;
        *(unsigned long long*)&xT[(4L << 22) + dst] = im4.v;
    }
}

// ---------------------------------------------------------------------------
// bf16 MFMA GEMM: C[z] = scale * A[z] . B(segmented) [+ I]
// A row-major [1024][Ktot], B segments are transposed planes [n][1024]
// 128x128 tile, 256 threads (4 waves, each 64x64 via 4x4 of 16x16x32 MFMA)
// ---------------------------------------------------------------------------
__global__ __launch_bounds__(256, 2) void gemm_bt_k(
    const ushort* __restrict__ Ab, long aPackStride, long aInnerStride, int aInnerDiv, int aLd,
    const ushort* __restrict__ Bb, SegOff segs, long bZStride,
    float* __restrict__ CreB, float* __restrict__ CimB, long cZStride, int cLd,
    int Ktot, int zHalf, float scale, int addI)
{
    __shared__ ushort As[128 * 32];
    __shared__ ushort Bs[128 * 32];

    const int z = blockIdx.z;
    const int pack = z / zHalf, inner = z % zHalf;
    const ushort* A = Ab + (long)pack * aPackStride + (long)(inner / aInnerDiv) * aInnerStride;
    float* C = (pack ? CimB : CreB) + (long)inner * cZStride;

    const int tid = threadIdx.x;
    const int lane = tid & 63, wave = tid >> 6;
    const int m0 = blockIdx.y * 128, n0 = blockIdx.x * 128;
    const int wm = (wave >> 1) * 64, wn = (wave & 1) * 64;
    const int l15 = lane & 15, quad = lane >> 4;

    f32x4 acc[4][4] = {};

    for (int kb = 0; kb < Ktot; kb += 32) {
        const ushort* Bp = Bb + segs.o[kb >> 10] + (long)inner * bZStride + (kb & 1023);
        #pragma unroll
        for (int q = 0; q < 2; ++q) {
            int c = q * 256 + wave * 64 + lane;
            gload16(A + (long)(m0 + (c >> 2)) * aLd + kb + (c & 3) * 8,
                    &As[(q * 256 + wave * 64) * 8]);
            gload16(Bp + (long)(n0 + (c >> 2)) * 1024 + (c & 3) * 8,
                    &Bs[(q * 256 + wave * 64) * 8]);
        }
        __syncthreads();
        bf16x8 af[4], bfr[4];
        #pragma unroll
        for (int i = 0; i < 4; ++i)
            af[i] = *(const bf16x8*)&As[(wm + i * 16 + l15) * 32 + quad * 8];
        #pragma unroll
        for (int j = 0; j < 4; ++j)
            bfr[j] = *(const bf16x8*)&Bs[(wn + j * 16 + l15) * 32 + quad * 8];
        #pragma unroll
        for (int i = 0; i < 4; ++i)
            #pragma unroll
            for (int j = 0; j < 4; ++j)
                acc[i][j] = __builtin_amdgcn_mfma_f32_16x16x32_bf16(af[i], bfr[j], acc[i][j], 0, 0, 0);
        __syncthreads();
    }

    #pragma unroll
    for (int i = 0; i < 4; ++i) {
        int row0 = m0 + wm + i * 16 + quad * 4;
        #pragma unroll
        for (int j = 0; j < 4; ++j) {
            int col = n0 + wn + j * 16 + l15;
            #pragma unroll
            for (int r = 0; r < 4; ++r) {
                float v = acc[i][j][r] * scale;
                if (addI && pack == 0 && (row0 + r) == col) v += 1.0f;
                C[(long)(row0 + r) * cLd + col] = v;
            }
        }
    }
}

// ---------------------------------------------------------------------------
extern "C" void kernel_launch(void* const* d_in, const int* in_sizes, int n_in,
                              void* d_out, int out_size, void* d_ws, size_t ws_size,
                              hipStream_t stream)
{
    const float* x_re = (const float*)d_in[0];
    const float* x_im = (const float*)d_in[1];
    const float* U_re = (const float*)d_in[2];
    const float* U_im = (const float*)d_in[3];
    float* out = (float*)d_out;

    // ws layout (160 MiB):
    //   [0,48M):   6 fp32 planes [2][1024][1024]: Tre,Tim,Rre,Rim,BSre,BSim
    //   [48,96M):  Askew bf16 [4][1024][6144]  (later reused as A_apply [4][1024][4096])
    //   [96,144M): At bf16 [4][1024][6144]   } reused as xT [2][4][4096][1024] (64 MiB)
    //   [144,160M): Tt bf16 [4][2][1024][1024] }
    float* fp = (float*)d_ws;
    float* Tre = fp + 0L * 2 * PLANE;
    float* Tim = fp + 1L * 2 * PLANE;
    float* Rre = fp + 2L * 2 * PLANE;
    float* Rim = fp + 3L * 2 * PLANE;
    float* BSre = fp + 4L * 2 * PLANE;
    float* BSim = fp + 5L * 2 * PLANE;
    ushort* Askew = (ushort*)((char*)d_ws + (48L << 20));
    ushort* At    = (ushort*)((char*)d_ws + (96L << 20));
    ushort* Tt    = (ushort*)((char*)d_ws + (144L << 20));
    ushort* Aap   = Askew;
    ushort* xT    = At;

    dim3 blk(256);

    const float scaleB = 1.0f / 512.0f;   // ||skew|| ~128 -> ||B|| ~0.25, s=9
    build_skew_k<<<dim3(2 * PLANE / 256), blk, 0, stream>>>(U_re, U_im, BSre, BSim, scaleB);
    init_T_k<<<dim3(2 * PLANE / 256), blk, 0, stream>>>(BSre, BSim, Tre, Tim, 1.0f / 8.0f);
    pack_A6_k<<<dim3(2048), blk, 0, stream>>>(BSre, BSim, Askew);

    SegOff se;
    se.o[0] = 0L;           se.o[1] = 2L * PLANE;  se.o[2] = 0L;
    se.o[3] = 4L * PLANE;   se.o[4] = 6L * PLANE;  se.o[5] = 4L * PLANE;

    dim3 ge(8, 8, 4);
    // Horner: T <- I + (B @ T)/j
    for (int j = 7; j >= 1; --j) {
        pack_BT6_k<<<dim3(16, 16, 2), blk, 0, stream>>>(Tre, Tim, Tt);
        gemm_bt_k<<<ge, blk, 0, stream>>>(Askew, 2L * 1024 * 6144, 1024L * 6144, 1, 6144,
                                          Tt, se, (long)PLANE,
                                          Rre, Rim, (long)PLANE, 1024,
                                          6144, 2, 1.0f / (float)j, 1);
        float* t;
        t = Tre; Tre = Rre; Rre = t;
        t = Tim; Tim = Rim; Rim = t;
    }
    // 9 squarings: T <- T @ T
    for (int s = 0; s < 9; ++s) {
        pack_A6_k<<<dim3(2048), blk, 0, stream>>>(Tre, Tim, At);
        pack_BT6_k<<<dim3(16, 16, 2), blk, 0, stream>>>(Tre, Tim, Tt);
        gemm_bt_k<<<ge, blk, 0, stream>>>(At, 2L * 1024 * 6144, 1024L * 6144, 1, 6144,
                                          Tt, se, (long)PLANE,
                                          Rre, Rim, (long)PLANE, 1024,
                                          6144, 2, 1.0f, 0);
        float* t;
        t = Tre; Tre = Rre; Rre = t;
        t = Tim; Tim = Rim; Rim = t;
    }

    // Apply: out[k,b1] = U[k] @ X[k,b1]
    pack_A4_k<<<dim3(2048), blk, 0, stream>>>(Tre, Tim, Aap);
    pack_xT_k<<<dim3(64, 16, 4), blk, 0, stream>>>(x_re, x_im, xT);

    SegOff sa;
    sa.o[0] = 0L;        sa.o[1] = 0L;
    sa.o[2] = 4L << 22;  sa.o[3] = 4L << 22;
    sa.o[4] = 0L;        sa.o[5] = 0L;

    gemm_bt_k<<<dim3(32, 8, 8), blk, 0, stream>>>(Aap, 2L * 1024 * 4096, 1024L * 4096, 2, 4096,
                                                  xT, sa, 1L << 22,
                                                  out, out + (1L << 24), 1L << 22, 4096,
                                                  4096, 4, 1.0f, 0);
}